// Round 1
// baseline (12926.079 us; speedup 1.0000x reference)
//
#include <hip/hip_runtime.h>
#include <stdint.h>

#define S_PER 262144        // 512*512 per channel
#define M_PER 200704        // 448*448 per channel
#define NCH   256           // 4*64 channels
#define BINS  65536
#define S_TOT 67108864ull   // 4*64*512*512

// ---------------- helpers ----------------
static __device__ __forceinline__ double blockReduceD(double v, double* sbuf) {
    int lane = threadIdx.x & 63;
    int wid  = threadIdx.x >> 6;
#pragma unroll
    for (int off = 32; off > 0; off >>= 1) v += __shfl_down(v, off, 64);
    if (lane == 0) sbuf[wid] = v;
    __syncthreads();
    double t = 0.0;
    if (threadIdx.x == 0) {
        int nw = blockDim.x >> 6;
        for (int i = 0; i < nw; ++i) t += sbuf[i];
    }
    return t;
}

static __device__ __forceinline__ uint32_t okey32(float f) {
    uint32_t u = __float_as_uint(f);
    return u ^ ((u & 0x80000000u) ? 0xFFFFFFFFu : 0x80000000u);
}

// ---------------- ref histogram ----------------
__global__ __launch_bounds__(256) void k_refhist(const float* __restrict__ ref,
                                                 uint32_t* __restrict__ H) {
    int ch = blockIdx.x / 784;
    int i  = (blockIdx.x % 784) * 256 + threadIdx.x;
    float v = ref[(size_t)ch * M_PER + i];
    uint32_t key = okey32(v) >> 16;
    atomicAdd(&H[((size_t)ch << 16) + key], 1u);
}

// ---------------- per-channel exclusive scan over 65536 bins ----------------
__global__ __launch_bounds__(1024) void k_scan(uint32_t* __restrict__ H) {
    __shared__ uint32_t s[1024];
    uint32_t* h = H + ((size_t)blockIdx.x << 16);
    const int tid = threadIdx.x;
    uint4 v[16];
    uint32_t sum = 0;
#pragma unroll
    for (int i = 0; i < 16; ++i) {
        v[i] = *(const uint4*)&h[tid * 64 + i * 4];
        sum += v[i].x + v[i].y + v[i].z + v[i].w;
    }
    s[tid] = sum;
    __syncthreads();
    for (int off = 1; off < 1024; off <<= 1) {
        uint32_t t = (tid >= off) ? s[tid - off] : 0u;
        __syncthreads();
        s[tid] += t;
        __syncthreads();
    }
    uint32_t run = s[tid] - sum;  // exclusive prefix of this thread's chunk
#pragma unroll
    for (int i = 0; i < 16; ++i) {
        uint4 o;
        o.x = run; run += v[i].x;
        o.y = run; run += v[i].y;
        o.z = run; run += v[i].z;
        o.w = run; run += v[i].w;
        *(uint4*)&h[tid * 64 + i * 4] = o;
    }
}

// ---------------- ref scatter into bucket-sorted R ----------------
__global__ __launch_bounds__(256) void k_refscatter(const float* __restrict__ ref,
                                                    uint32_t* __restrict__ H,
                                                    float* __restrict__ R) {
    int ch = blockIdx.x / 784;
    int i  = (blockIdx.x % 784) * 256 + threadIdx.x;
    float v = ref[(size_t)ch * M_PER + i];
    uint32_t key = okey32(v) >> 16;
    uint32_t slot = atomicAdd(&H[((size_t)ch << 16) + key], 1u);
    R[(size_t)ch * M_PER + slot] = v;
}

// ---------------- conv + feat + content partials + src histogram ----------------
__global__ __launch_bounds__(256) void k_conv(const float* __restrict__ img,
                                              const float* __restrict__ cw,
                                              const float* __restrict__ cb,
                                              const float* __restrict__ ct,
                                              float* __restrict__ feat,
                                              uint32_t* __restrict__ H,
                                              double* __restrict__ accs) {
    __shared__ float sIn[3][18][18];
    __shared__ float sW[64 * 27];
    __shared__ float sB[64];
    __shared__ double sRed[4];
    const int n = blockIdx.z, ty = blockIdx.y, tx = blockIdx.x;
    const int tid = threadIdx.x;
    for (int i = tid; i < 64 * 27; i += 256) sW[i] = cw[i];
    if (tid < 64) sB[tid] = cb[tid];
    const float mean_[3] = {0.485f, 0.456f, 0.406f};
    const float std_[3]  = {0.229f, 0.224f, 0.225f};
    for (int i = tid; i < 3 * 18 * 18; i += 256) {
        int c = i / 324, r = i % 324, yy = r / 18, xx = r % 18;
        int gy = ty * 16 + yy - 1, gx = tx * 16 + xx - 1;
        float v = 0.0f;
        if (gy >= 0 && gy < 512 && gx >= 0 && gx < 512)
            v = (img[((size_t)n * 3 + c) * (size_t)S_PER + (size_t)gy * 512 + gx] - mean_[c]) / std_[c];
        sIn[c][yy][xx] = v;
    }
    __syncthreads();
    const int x = tid & 15, y = tid >> 4;
    float xin[27];
#pragma unroll
    for (int c = 0; c < 3; ++c)
#pragma unroll
        for (int ky = 0; ky < 3; ++ky)
#pragma unroll
            for (int kx = 0; kx < 3; ++kx)
                xin[c * 9 + ky * 3 + kx] = sIn[c][y + ky][x + kx];
    const int gy = ty * 16 + y, gx = tx * 16 + x;
    const size_t pbase = (size_t)n * 64 * (size_t)S_PER + (size_t)gy * 512 + gx;
    double cacc = 0.0;
    const int lane = tid & 63;
    for (int oc = 0; oc < 64; ++oc) {
        float s = sB[oc];
#pragma unroll
        for (int t = 0; t < 27; ++t) s = fmaf(sW[oc * 27 + t], xin[t], s);
        float f = s > 0.0f ? s : 0.0f;
        size_t off = pbase + (size_t)oc * S_PER;
        feat[off] = f;
        float d = f - ct[off];
        cacc += (double)d * (double)d;
        uint32_t key = __float_as_uint(f) >> 16;
        unsigned long long mz = __ballot(key == 0u);
        if (key == 0u) {
            int leader = __builtin_ctzll(mz);
            if (lane == leader)
                atomicAdd(&H[(((size_t)n * 64 + oc) << 16)], (uint32_t)__popcll(mz));
        } else {
            atomicAdd(&H[(((size_t)n * 64 + oc) << 16) + key], 1u);
        }
    }
    double tot = blockReduceD(cacc, sRed);
    if (tid == 0) atomicAdd(&accs[0], tot);
}

// ---------------- gram: G[n] += F F^T over a 4096-position slab ----------------
__global__ __launch_bounds__(256) void k_gram(const float* __restrict__ feat,
                                              float* __restrict__ G) {
    __shared__ float L[256][68];
    const int n = blockIdx.x >> 6, sb = blockIdx.x & 63;
    const int tid = threadIdx.x;
    const int w = tid >> 6, lane = tid & 63, r = lane >> 3, q = lane & 7;
    float acc[8][8];
#pragma unroll
    for (int i = 0; i < 8; ++i)
#pragma unroll
        for (int j = 0; j < 8; ++j) acc[i][j] = 0.0f;
    const size_t base = (size_t)sb * 4096;
    for (int chunk = 0; chunk < 16; ++chunk) {
        __syncthreads();
        size_t pb = base + (size_t)chunk * 256 + tid;
#pragma unroll 8
        for (int c = 0; c < 64; ++c)
            L[tid][c] = feat[((size_t)n * 64 + c) * (size_t)S_PER + pb];
        __syncthreads();
        for (int pp = 0; pp < 64; ++pp) {
            int p = (w << 6) + pp;
            const float4 a0 = *(const float4*)&L[p][r * 8];
            const float4 a1 = *(const float4*)&L[p][r * 8 + 4];
            const float4 b0 = *(const float4*)&L[p][q * 8];
            const float4 b1 = *(const float4*)&L[p][q * 8 + 4];
            float a[8] = {a0.x, a0.y, a0.z, a0.w, a1.x, a1.y, a1.z, a1.w};
            float b[8] = {b0.x, b0.y, b0.z, b0.w, b1.x, b1.y, b1.z, b1.w};
#pragma unroll
            for (int i = 0; i < 8; ++i)
#pragma unroll
                for (int j = 0; j < 8; ++j)
                    acc[i][j] = fmaf(a[i], b[j], acc[i][j]);
        }
    }
#pragma unroll
    for (int i = 0; i < 8; ++i)
#pragma unroll
        for (int j = 0; j < 8; ++j)
            atomicAdd(&G[((size_t)n * 64 + r * 8 + i) * 64 + q * 8 + j], acc[i][j]);
}

// ---------------- style loss ----------------
__global__ __launch_bounds__(256) void k_style(const float* __restrict__ G,
                                               const float* __restrict__ target,
                                               double* __restrict__ accs) {
    __shared__ double sRed[4];
    int i = blockIdx.x * 256 + threadIdx.x;
    float g = G[i] * (1.0f / 16777216.0f);
    float d = g - target[i];
    double tot = blockReduceD((double)d * (double)d, sRed);
    if (threadIdx.x == 0) atomicAdd(&accs[1], tot);
}

// ---------------- pass B: rank src elements, gather resampled ref, accumulate ----------------
__global__ __launch_bounds__(256) void k_passB(const float* __restrict__ feat,
                                               const float* __restrict__ R,
                                               uint32_t* __restrict__ H,
                                               double* __restrict__ accs) {
    __shared__ double sRed[4];
    // XCD swizzle: each XCD (blockIdx%8) works through its own 32 channels so the
    // channel's 800KB R window stays resident in that XCD's L2.
    const int bi  = blockIdx.x;
    const int xcd = bi & 7;
    const int j   = bi >> 3;              // 0..8191
    const int ch  = xcd * 32 + (j >> 8);  // 0..255
    const int blk = j & 255;              // 256 blocks per channel
    const int tid = threadIdx.x, lane = tid & 63;
    const size_t ebase = (size_t)ch * S_PER + (size_t)blk * 1024 + (size_t)tid * 4;
    const float4 f4 = *(const float4*)&feat[ebase];
    uint32_t* h = H + ((size_t)ch << 16);
    const float* r = R + (size_t)ch * M_PER;
    const double SC = 200703.0 / 262143.0;  // (M-1)/(S-1)
    double acc = 0.0;
    float vv[4] = {f4.x, f4.y, f4.z, f4.w};
#pragma unroll
    for (int e = 0; e < 4; ++e) {
        float v = vv[e];
        uint32_t key = __float_as_uint(v) >> 16;
        unsigned long long mz = __ballot(key == 0u);
        uint32_t basep = 0;
        int leader = 0;
        if (mz) leader = __builtin_ctzll(mz);
        if (key == 0u && lane == leader)
            basep = atomicAdd(&h[0], (uint32_t)__popcll(mz));
        if (mz) basep = (uint32_t)__shfl((int)basep, leader, 64);
        uint32_t slot;
        if (key == 0u)
            slot = basep + (uint32_t)__popcll(mz & ((1ull << lane) - 1ull));
        else
            slot = atomicAdd(&h[key], 1u);
        double pos = (double)slot * SC;
        int lo = (int)pos;
        float wgt = (float)(pos - (double)lo);
        int hi = lo + 1; if (hi > 200703) hi = 200703;
        float rl = r[lo], rh = r[hi];
        float b = rl * (1.0f - wgt) + rh * wgt;
        float d = v - b;
        acc += (double)d * (double)d;
    }
    double tot = blockReduceD(acc, sRed);
    if (tid == 0) atomicAdd(&accs[2], tot);
}

// ---------------- finalize ----------------
__global__ void k_final(const double* __restrict__ accs, float* __restrict__ out) {
    if (threadIdx.x == 0) {
        out[S_TOT + 0] = (float)(accs[0] / 67108864.0);
        out[S_TOT + 1] = (float)(accs[1] / 16384.0);
        out[S_TOT + 2] = (float)(accs[2] / 67108864.0);
    }
}

__global__ void k_sentinel(float* out) { out[0] = 1.0e8f; }

extern "C" void kernel_launch(void* const* d_in, const int* in_sizes, int n_in,
                              void* d_out, int out_size, void* d_ws, size_t ws_size,
                              hipStream_t stream) {
    const float* img = (const float*)d_in[0];
    const float* cw  = (const float*)d_in[1];
    const float* cb  = (const float*)d_in[2];
    const float* ct  = (const float*)d_in[3];
    const float* st  = (const float*)d_in[4];
    const float* ht  = (const float*)d_in[5];
    float* out = (float*)d_out;

    // ws layout
    const size_t OFF_R    = 0;                      // float[256*200704]  = 205,520,896 B
    const size_t OFF_H    = 205520896;              // uint32[256*65536] =  67,108,864 B
    const size_t OFF_G    = 272629760;              // float[4*64*64]    =      65,536 B
    const size_t OFF_ACC  = 272695296;              // double[4]
    const size_t REQUIRED = 272695328 + 64;

    if (ws_size < REQUIRED) {  // loud, distinguishable failure
        k_sentinel<<<1, 1, 0, stream>>>(out);
        return;
    }
    char* ws = (char*)d_ws;
    float*    R    = (float*)(ws + OFF_R);
    uint32_t* H    = (uint32_t*)(ws + OFF_H);
    float*    G    = (float*)(ws + OFF_G);
    double*   accs = (double*)(ws + OFF_ACC);

    hipMemsetAsync(H, 0, 67108864, stream);
    hipMemsetAsync(G, 0, 65536 + 32, stream);  // gram + accumulators

    // ref side: histogram -> scan -> scatter into bucket-sorted R
    k_refhist<<<NCH * 784, 256, 0, stream>>>(ht, H);
    k_scan<<<NCH, 1024, 0, stream>>>(H);
    k_refscatter<<<NCH * 784, 256, 0, stream>>>(ht, H, R);

    // src side: conv + feat + content loss + src histogram (fresh H)
    hipMemsetAsync(H, 0, 67108864, stream);
    k_conv<<<dim3(32, 32, 4), 256, 0, stream>>>(img, cw, cb, ct, out, H, accs);

    // gram + style loss
    k_gram<<<NCH, 256, 0, stream>>>(out, G);
    k_style<<<64, 256, 0, stream>>>(G, st, accs);

    // scan src histogram, then rank-and-accumulate hist loss
    k_scan<<<NCH, 1024, 0, stream>>>(H);
    k_passB<<<65536, 256, 0, stream>>>(out, R, H, accs);

    k_final<<<1, 64, 0, stream>>>(accs, out);
}

// Round 2
// 5453.934 us; speedup vs baseline: 2.3700x; 2.3700x over previous
//
#include <hip/hip_runtime.h>
#include <stdint.h>

#define S_PER 262144        // 512*512 per channel
#define M_PER 200704        // 448*448 per channel
#define NCH   256           // 4*64 channels
#define S_TOT 67108864ull   // 4*64*512*512
#define SCD   (200703.0/262143.0)   // (M-1)/(S-1)

// ---------------- helpers ----------------
static __device__ __forceinline__ double blockReduceD(double v, double* sbuf) {
    int lane = threadIdx.x & 63;
    int wid  = threadIdx.x >> 6;
#pragma unroll
    for (int off = 32; off > 0; off >>= 1) v += __shfl_down(v, off, 64);
    if (lane == 0) sbuf[wid] = v;
    __syncthreads();
    double t = 0.0;
    if (threadIdx.x == 0) {
        int nw = blockDim.x >> 6;
        for (int i = 0; i < nw; ++i) t += sbuf[i];
    }
    return t;
}

static __device__ __forceinline__ uint32_t okey32(float f) {
    uint32_t u = __float_as_uint(f);
    return u ^ ((u & 0x80000000u) ? 0xFFFFFFFFu : 0x80000000u);
}

// ---------------- ref histogram: one workgroup per channel (XCD-local atomics) ----------------
__global__ __launch_bounds__(1024) void k_refhist2(const float* __restrict__ ref,
                                                   uint32_t* __restrict__ H) {
    const int ch = blockIdx.x;
    const float4* src = (const float4*)(ref + (size_t)ch * M_PER);
    uint32_t* h = H + ((size_t)ch << 16);
    for (int i = threadIdx.x; i < M_PER / 4; i += 1024) {
        float4 v = src[i];
        atomicAdd(&h[okey32(v.x) >> 16], 1u);
        atomicAdd(&h[okey32(v.y) >> 16], 1u);
        atomicAdd(&h[okey32(v.z) >> 16], 1u);
        atomicAdd(&h[okey32(v.w) >> 16], 1u);
    }
}

// ---------------- per-channel exclusive scan over 65536 bins ----------------
__global__ __launch_bounds__(1024) void k_scan(uint32_t* __restrict__ H) {
    __shared__ uint32_t s[1024];
    uint32_t* h = H + ((size_t)blockIdx.x << 16);
    const int tid = threadIdx.x;
    uint4 v[16];
    uint32_t sum = 0;
#pragma unroll
    for (int i = 0; i < 16; ++i) {
        v[i] = *(const uint4*)&h[tid * 64 + i * 4];
        sum += v[i].x + v[i].y + v[i].z + v[i].w;
    }
    s[tid] = sum;
    __syncthreads();
    for (int off = 1; off < 1024; off <<= 1) {
        uint32_t t = (tid >= off) ? s[tid - off] : 0u;
        __syncthreads();
        s[tid] += t;
        __syncthreads();
    }
    uint32_t run = s[tid] - sum;
#pragma unroll
    for (int i = 0; i < 16; ++i) {
        uint4 o;
        o.x = run; run += v[i].x;
        o.y = run; run += v[i].y;
        o.z = run; run += v[i].z;
        o.w = run; run += v[i].w;
        *(uint4*)&h[tid * 64 + i * 4] = o;
    }
}

// ---------------- ref scatter into bucket-sorted R: one workgroup per channel ----------------
__global__ __launch_bounds__(1024) void k_refscatter2(const float* __restrict__ ref,
                                                      uint32_t* __restrict__ H,
                                                      float* __restrict__ R) {
    const int ch = blockIdx.x;
    const float4* src = (const float4*)(ref + (size_t)ch * M_PER);
    uint32_t* h = H + ((size_t)ch << 16);
    float* r = R + (size_t)ch * M_PER;
    for (int i = threadIdx.x; i < M_PER / 4; i += 1024) {
        float4 v = src[i];
        float c[4] = {v.x, v.y, v.z, v.w};
#pragma unroll
        for (int e = 0; e < 4; ++e) {
            uint32_t slot = atomicAdd(&h[okey32(c[e]) >> 16], 1u);
            r[slot] = c[e];
        }
    }
}

// ---------------- sum over slots of r(slot)^2 (exact, streaming, no contention) ----------------
__global__ __launch_bounds__(256) void k_slotsq(const float* __restrict__ R,
                                                double* __restrict__ accs) {
    __shared__ double sRed[4];
    const size_t sbase = (size_t)blockIdx.x * 4096;
    const int ch = (int)(sbase >> 18);
    const float* r = R + (size_t)ch * M_PER;
    double acc = 0.0;
#pragma unroll 4
    for (int k = 0; k < 16; ++k) {
        int slot = (int)(sbase & 262143) + k * 256 + threadIdx.x;
        double pos = slot * SCD;
        int lo = (int)pos;
        double w = pos - (double)lo;
        int hi = lo + 1; if (hi > M_PER - 1) hi = M_PER - 1;
        double rv = (1.0 - w) * (double)r[lo] + w * (double)r[hi];
        acc += rv * rv;
    }
    double t = blockReduceD(acc, sRed);
    if (threadIdx.x == 0) atomicAdd(&accs[2], t);
}

// ---------------- 3-pass in-place prefix scan of R -> AR (per channel) ----------------
__global__ __launch_bounds__(256) void k_scanR1(const float* __restrict__ R,
                                                double* __restrict__ Bsum) {
    __shared__ double sRed[4];
    const size_t base = (size_t)blockIdx.x * 4096 + (size_t)threadIdx.x * 16;
    const float4* p = (const float4*)(R + base);
    double s = 0.0;
#pragma unroll
    for (int k = 0; k < 4; ++k) {
        float4 v = p[k];
        s += (double)v.x + (double)v.y + (double)v.z + (double)v.w;
    }
    double t = blockReduceD(s, sRed);
    if (threadIdx.x == 0) Bsum[blockIdx.x] = t;
}

__global__ __launch_bounds__(64) void k_scanR2(const double* __restrict__ Bsum,
                                               double* __restrict__ Boff,
                                               double* __restrict__ Tot) {
    if (threadIdx.x == 0) {
        const int ch = blockIdx.x;
        double run = 0.0;
        for (int j = 0; j < 49; ++j) {
            Boff[ch * 49 + j] = run;
            run += Bsum[ch * 49 + j];
        }
        Tot[ch] = run;
    }
}

__global__ __launch_bounds__(256) void k_scanR3(float* __restrict__ R,
                                                const double* __restrict__ Boff) {
    __shared__ double sth[256];
    const size_t base = (size_t)blockIdx.x * 4096 + (size_t)threadIdx.x * 16;
    float4* p = (float4*)(R + base);
    float4 v[4];
    double vals[16];
#pragma unroll
    for (int k = 0; k < 4; ++k) v[k] = p[k];
#pragma unroll
    for (int k = 0; k < 4; ++k) {
        vals[k * 4 + 0] = v[k].x; vals[k * 4 + 1] = v[k].y;
        vals[k * 4 + 2] = v[k].z; vals[k * 4 + 3] = v[k].w;
    }
    double thsum = 0.0;
#pragma unroll
    for (int k = 0; k < 16; ++k) thsum += vals[k];
    sth[threadIdx.x] = thsum;
    __syncthreads();
    for (int off = 1; off < 256; off <<= 1) {
        double t = (threadIdx.x >= (unsigned)off) ? sth[threadIdx.x - off] : 0.0;
        __syncthreads();
        sth[threadIdx.x] += t;
        __syncthreads();
    }
    double run = Boff[blockIdx.x] + (sth[threadIdx.x] - thsum);  // exclusive
#pragma unroll
    for (int k = 0; k < 4; ++k) {
        float4 o;
        o.x = (float)run; run += vals[k * 4 + 0];
        o.y = (float)run; run += vals[k * 4 + 1];
        o.z = (float)run; run += vals[k * 4 + 2];
        o.w = (float)run; run += vals[k * 4 + 3];
        p[k] = o;
    }
}

// ---------------- conv + feat + content partials (no atomics on hot path) ----------------
__global__ __launch_bounds__(256) void k_conv(const float* __restrict__ img,
                                              const float* __restrict__ cw,
                                              const float* __restrict__ cb,
                                              const float* __restrict__ ct,
                                              float* __restrict__ feat,
                                              double* __restrict__ accs) {
    __shared__ float sIn[3][18][18];
    __shared__ float sW[64 * 27];
    __shared__ float sB[64];
    __shared__ double sRed[4];
    const int n = blockIdx.z, ty = blockIdx.y, tx = blockIdx.x;
    const int tid = threadIdx.x;
    for (int i = tid; i < 64 * 27; i += 256) sW[i] = cw[i];
    if (tid < 64) sB[tid] = cb[tid];
    const float mean_[3] = {0.485f, 0.456f, 0.406f};
    const float std_[3]  = {0.229f, 0.224f, 0.225f};
    for (int i = tid; i < 3 * 18 * 18; i += 256) {
        int c = i / 324, r = i % 324, yy = r / 18, xx = r % 18;
        int gy = ty * 16 + yy - 1, gx = tx * 16 + xx - 1;
        float v = 0.0f;
        if (gy >= 0 && gy < 512 && gx >= 0 && gx < 512)
            v = (img[((size_t)n * 3 + c) * (size_t)S_PER + (size_t)gy * 512 + gx] - mean_[c]) / std_[c];
        sIn[c][yy][xx] = v;
    }
    __syncthreads();
    const int x = tid & 15, y = tid >> 4;
    float xin[27];
#pragma unroll
    for (int c = 0; c < 3; ++c)
#pragma unroll
        for (int ky = 0; ky < 3; ++ky)
#pragma unroll
            for (int kx = 0; kx < 3; ++kx)
                xin[c * 9 + ky * 3 + kx] = sIn[c][y + ky][x + kx];
    const int gy = ty * 16 + y, gx = tx * 16 + x;
    const size_t pbase = (size_t)n * 64 * (size_t)S_PER + (size_t)gy * 512 + gx;
    double cacc = 0.0;
    for (int oc = 0; oc < 64; ++oc) {
        float s = sB[oc];
#pragma unroll
        for (int t = 0; t < 27; ++t) s = fmaf(sW[oc * 27 + t], xin[t], s);
        float f = s > 0.0f ? s : 0.0f;
        size_t off = pbase + (size_t)oc * S_PER;
        feat[off] = f;
        float d = f - ct[off];
        cacc += (double)d * (double)d;
    }
    double tot = blockReduceD(cacc, sRed);
    if (tid == 0) atomicAdd(&accs[0], tot);
}

// ---------------- src histogram: one workgroup per channel, zeros counted privately ----------------
__global__ __launch_bounds__(1024) void k_srchist2(const float* __restrict__ feat,
                                                   uint32_t* __restrict__ H) {
    const int ch = blockIdx.x;
    const float4* src = (const float4*)(feat + (size_t)ch * S_PER);
    uint32_t* h = H + ((size_t)ch << 16);
    uint32_t zc = 0;
    for (int i = threadIdx.x; i < S_PER / 4; i += 1024) {
        float4 v = src[i];
        float c[4] = {v.x, v.y, v.z, v.w};
#pragma unroll
        for (int e = 0; e < 4; ++e) {
            uint32_t key = __float_as_uint(c[e]) >> 16;
            if (key == 0u) zc++;
            else atomicAdd(&h[key], 1u);
        }
    }
    if (zc) atomicAdd(&h[0], zc);
}

// ---------------- cross term: one thread per 4 buckets, zero at'omics on hot path ----------------
__global__ __launch_bounds__(256) void k_cross(const float* __restrict__ AR,
                                               const uint32_t* __restrict__ H,
                                               const double* __restrict__ Tot,
                                               double* __restrict__ accs) {
    __shared__ double sRed[4];
    const int ch = blockIdx.x >> 6;
    const int bblk = blockIdx.x & 63;
    const uint32_t* hp = H + ((size_t)ch << 16);
    const float* ar = AR + (size_t)ch * M_PER;
    const double tot = Tot[ch];
    const int b0 = bblk * 1024 + threadIdx.x * 4;
    uint4 P = *(const uint4*)&hp[b0];
    uint32_t p4 = (b0 + 4 < 65536) ? hp[b0 + 4] : (uint32_t)S_PER;
    uint32_t Pn[5] = {P.x, P.y, P.z, P.w, p4};
    double acc = 0.0;
#pragma unroll
    for (int e = 0; e < 4; ++e) {
        int bb = b0 + e;
        uint32_t c = Pn[e + 1] - Pn[e];
        if (c == 0u || bb == 0) continue;
        float vstar = __uint_as_float(((uint32_t)bb << 16) | 0x8000u);
        double lox = (double)Pn[e] * SCD, hix = (double)Pn[e + 1] * SCD;
        int ml = (int)lox; double fl = lox - (double)ml;
        int mh = (int)hix; double fh = hix - (double)mh;
        double ARl = (double)ar[ml];
        double ARh = (double)ar[mh];
        double Rl = ((ml + 1 < M_PER) ? (double)ar[ml + 1] : tot) - ARl;
        double Rh = ((mh + 1 < M_PER) ? (double)ar[mh + 1] : tot) - ARh;
        acc += (double)vstar * ((ARh + fh * Rh) - (ARl + fl * Rl));
    }
    double t = blockReduceD(acc, sRed);
    if (threadIdx.x == 0) atomicAdd(&accs[3], t);
}

// ---------------- gram: G[n] += F F^T over a 4096-position slab ----------------
__global__ __launch_bounds__(256) void k_gram(const float* __restrict__ feat,
                                              float* __restrict__ G) {
    __shared__ float L[256][68];
    const int n = blockIdx.x >> 6, sb = blockIdx.x & 63;
    const int tid = threadIdx.x;
    const int w = tid >> 6, lane = tid & 63, r = lane >> 3, q = lane & 7;
    float acc[8][8];
#pragma unroll
    for (int i = 0; i < 8; ++i)
#pragma unroll
        for (int j = 0; j < 8; ++j) acc[i][j] = 0.0f;
    const size_t base = (size_t)sb * 4096;
    for (int chunk = 0; chunk < 16; ++chunk) {
        __syncthreads();
        size_t pb = base + (size_t)chunk * 256 + tid;
#pragma unroll 8
        for (int c = 0; c < 64; ++c)
            L[tid][c] = feat[((size_t)n * 64 + c) * (size_t)S_PER + pb];
        __syncthreads();
        for (int pp = 0; pp < 64; ++pp) {
            int p = (w << 6) + pp;
            const float4 a0 = *(const float4*)&L[p][r * 8];
            const float4 a1 = *(const float4*)&L[p][r * 8 + 4];
            const float4 b0 = *(const float4*)&L[p][q * 8];
            const float4 b1 = *(const float4*)&L[p][q * 8 + 4];
            float a[8] = {a0.x, a0.y, a0.z, a0.w, a1.x, a1.y, a1.z, a1.w};
            float b[8] = {b0.x, b0.y, b0.z, b0.w, b1.x, b1.y, b1.z, b1.w};
#pragma unroll
            for (int i = 0; i < 8; ++i)
#pragma unroll
                for (int j = 0; j < 8; ++j)
                    acc[i][j] = fmaf(a[i], b[j], acc[i][j]);
        }
    }
#pragma unroll
    for (int i = 0; i < 8; ++i)
#pragma unroll
        for (int j = 0; j < 8; ++j)
            atomicAdd(&G[((size_t)n * 64 + r * 8 + i) * 64 + q * 8 + j], acc[i][j]);
}

// ---------------- style loss ----------------
__global__ __launch_bounds__(256) void k_style(const float* __restrict__ G,
                                               const float* __restrict__ target,
                                               double* __restrict__ accs) {
    __shared__ double sRed[4];
    int i = blockIdx.x * 256 + threadIdx.x;
    float g = G[i] * (1.0f / 16777216.0f);
    float d = g - target[i];
    double tot = blockReduceD((double)d * (double)d, sRed);
    if (threadIdx.x == 0) atomicAdd(&accs[1], tot);
}

// ---------------- finalize: Sum(v^2) from gram diag + assemble losses ----------------
__global__ __launch_bounds__(256) void k_final(const float* __restrict__ G,
                                               const double* __restrict__ accs,
                                               float* __restrict__ out) {
    __shared__ double sRed[4];
    const int t = threadIdx.x;           // 256 = (n, c)
    const int n = t >> 6, c = t & 63;
    double diag = (double)G[(size_t)n * 4096 + (size_t)c * 65];
    double sd = blockReduceD(diag, sRed);
    if (t == 0) {
        double hist = sd + accs[2] - 2.0 * (accs[3] / SCD);
        out[S_TOT + 0] = (float)(accs[0] / 67108864.0);
        out[S_TOT + 1] = (float)(accs[1] / 16384.0);
        out[S_TOT + 2] = (float)(hist / 67108864.0);
    }
}

__global__ void k_sentinel(float* out) { out[0] = 1.0e8f; }

extern "C" void kernel_launch(void* const* d_in, const int* in_sizes, int n_in,
                              void* d_out, int out_size, void* d_ws, size_t ws_size,
                              hipStream_t stream) {
    const float* img = (const float*)d_in[0];
    const float* cw  = (const float*)d_in[1];
    const float* cb  = (const float*)d_in[2];
    const float* ct  = (const float*)d_in[3];
    const float* st  = (const float*)d_in[4];
    const float* ht  = (const float*)d_in[5];
    float* out = (float*)d_out;

    // ws layout
    const size_t OFF_R   = 0;                       // float[256*200704]  = 205,520,896 B (R, later AR in-place)
    const size_t OFF_H   = 205520896;               // uint32[256*65536] =  67,108,864 B
    const size_t OFF_G   = 272629760;               // float[4*64*64]    =      65,536 B
    const size_t OFF_TOT = 272695296;               // double[256]       =       2,048 B
    const size_t OFF_ACC = 272697344;               // double[4]
    const size_t REQUIRED = 272697408;

    if (ws_size < REQUIRED) {
        k_sentinel<<<1, 1, 0, stream>>>(out);
        return;
    }
    char* ws = (char*)d_ws;
    float*    R    = (float*)(ws + OFF_R);
    uint32_t* H    = (uint32_t*)(ws + OFF_H);
    float*    G    = (float*)(ws + OFF_G);
    double*   Tot  = (double*)(ws + OFF_TOT);
    double*   accs = (double*)(ws + OFF_ACC);
    // Bsum/Boff live inside H's space while H is dead (between refscatter and src memset)
    double* Bsum = (double*)(ws + OFF_H);           // 12544 * 8 = 100,352 B
    double* Boff = (double*)(ws + OFF_H + 131072);  // 12544 * 8

    hipMemsetAsync(H, 0, 67108864, stream);
    hipMemsetAsync(G, 0, 65536 + 2048 + 64, stream);  // gram + Tot + accs

    // ref side: per-channel histogram -> scan -> scatter into bucket-sorted R
    k_refhist2<<<NCH, 1024, 0, stream>>>(ht, H);
    k_scan<<<NCH, 1024, 0, stream>>>(H);
    k_refscatter2<<<NCH, 1024, 0, stream>>>(ht, H, R);

    // sum_slot r(slot)^2 (needs raw sorted R), then convert R -> prefix AR in place
    k_slotsq<<<16384, 256, 0, stream>>>(R, accs);
    k_scanR1<<<12544, 256, 0, stream>>>(R, Bsum);
    k_scanR2<<<NCH, 64, 0, stream>>>(Bsum, Boff, Tot);
    k_scanR3<<<12544, 256, 0, stream>>>(R, Boff);

    // conv + feat + content loss
    k_conv<<<dim3(32, 32, 4), 256, 0, stream>>>(img, cw, cb, ct, out, accs);

    // src histogram (counts only) -> scan -> cross term
    hipMemsetAsync(H, 0, 67108864, stream);
    k_srchist2<<<NCH, 1024, 0, stream>>>(out, H);
    k_scan<<<NCH, 1024, 0, stream>>>(H);
    k_cross<<<16384, 256, 0, stream>>>(R, H, Tot, accs);

    // gram + style loss
    k_gram<<<NCH, 256, 0, stream>>>(out, G);
    k_style<<<64, 256, 0, stream>>>(G, st, accs);

    k_final<<<1, 256, 0, stream>>>(G, accs, out);
}